// Round 9
// baseline (250.255 us; speedup 1.0000x reference)
//
#include <hip/hip_runtime.h>
#include <math.h>

#define NN 4096
#define LN_EPS 1e-5f
#define EPS 1e-8f

typedef unsigned short ushortT;
typedef unsigned int uintT;
typedef __attribute__((ext_vector_type(8))) short short8;
typedef __attribute__((ext_vector_type(4))) float f32x4;
typedef __attribute__((ext_vector_type(2))) float f32x2;
typedef __attribute__((ext_vector_type(4))) unsigned short us4;

// workspace offsets (floats) — qU/ready/slotsV deleted (redundant-update
// protocol: slots + q' live in registers). Total ~3.4 MB.
// RESUBMIT of R8: bench infra failed ("container failed twice") with no
// kernel signal. Deadlock audit (see session journal): co-residency (2/CU,
// 512 blocks) was already required and proven by passing R5-R7; cnt bumps
// strictly precede any spin on them; LDS regions disjoint. Unchanged retry.
#define OFF_AP    0L         // accPart [it3][b][e8][512] f32 = 786432
#define OFF_CP    786432L    // colPart [it3][b][e8][8] f32 = 12288
#define OFF_WIHP  798720L    // w_ih packed [f][lane][4] = 16384
#define OFF_WHHP  815104L    // w_hh packed [f][lane][4] = 16384
#define OFF_W1P   831488L    // mlp_w1 packed [f][lane][2] = 8192
#define OFF_W2T   839680L    // mlp_w2^T [128][64] = 8192
#define OFF_WQT   847872L    // Wq^T [64][64] = 4096
#define OFF_WVT   851968L    // Wv^T [f][d] = 4096
#define OFF_CNT   856064L    // uint cnt[3*64]

__device__ __forceinline__ float wredsum(float v) {
#pragma unroll
  for (int off = 32; off > 0; off >>= 1) v += __shfl_xor(v, off);
  return v;
}

__device__ __forceinline__ ushortT f2bf(float f) {
  uintT b = __float_as_uint(f);
  b += 0x7fff + ((b >> 16) & 1);          // RNE
  return (ushortT)(b >> 16);
}

// coherent (memory-side) stores/loads for the cross-block protocol (no RMW
// except the single cnt bump per block per iteration).
__device__ __forceinline__ void store2_coh(float* p, f32x2 v) {
  asm volatile("global_store_dwordx2 %0, %1, off sc0 sc1" :: "v"(p), "v"(v) : "memory");
}
__device__ __forceinline__ void store1f_coh(float* p, float v) {
  asm volatile("global_store_dword %0, %1, off sc0 sc1" :: "v"(p), "v"(v) : "memory");
}
__device__ __forceinline__ uintT load1u_coh(const uintT* p) {
  uintT r;
  asm volatile("global_load_dword %0, %1, off sc0 sc1\n\t"
               "s_waitcnt vmcnt(0)" : "=v"(r) : "v"(p) : "memory");
  return r;
}
__device__ __forceinline__ void drain_vm() {
  asm volatile("s_waitcnt vmcnt(0)" ::: "memory");
}
__device__ __forceinline__ void wait_lds() {
  asm volatile("s_waitcnt lgkmcnt(0)" ::: "memory");
}

// ---------------------------------------------------------------------------
// K0: weight prep (packed layouts for the update GEMVs) + cnt zero.
// wihP[(f*64+l)*4+g] = w_ih[(g*64+l)*64+f] (g<3; g=3 pad 0) -> one dwordx4
// per f per matrix in the GRU loop instead of 3 stride-256B scalars.
__global__ __launch_bounds__(256) void k_prep(
    const float* __restrict__ w_ih, const float* __restrict__ w_hh,
    const float* __restrict__ w1, const float* __restrict__ w2,
    const float* __restrict__ Wq, const float* __restrict__ Wv,
    float* __restrict__ wihP, float* __restrict__ whhP,
    float* __restrict__ w1P, float* __restrict__ w2T, float* __restrict__ wqT,
    float* __restrict__ wvT, uintT* __restrict__ cnt)
{
  int idx = blockIdx.x * 256 + threadIdx.x;
  if (idx < 16384) {
    int g = idx & 3, l = (idx >> 2) & 63, f = idx >> 8;
    wihP[idx] = (g < 3) ? w_ih[(g * 64 + l) * 64 + f] : 0.f;
  } else if (idx < 32768) {
    int i = idx - 16384;
    int g = i & 3, l = (i >> 2) & 63, f = i >> 8;
    whhP[i] = (g < 3) ? w_hh[(g * 64 + l) * 64 + f] : 0.f;
  } else if (idx < 40960) {
    int i = idx - 32768;
    int g = i & 1, l = (i >> 1) & 63, f = i >> 7;
    w1P[i] = w1[(g * 64 + l) * 64 + f];
  } else if (idx < 49152) {
    int i = idx - 40960; int d = i >> 7, j = i & 127;
    w2T[j * 64 + d] = w2[i];
  } else if (idx < 53248) {
    int i = idx - 49152; int e = i >> 6, d = i & 63;
    wqT[d * 64 + e] = Wq[i];
  } else if (idx < 57344) {
    int i = idx - 53248; int d = i >> 6, f = i & 63;
    wvT[f * 64 + d] = Wv[i];         // wvT[f][d] = Wv[d][f]
  } else if (idx < 57536) {
    cnt[idx - 57344] = 0u;
  }
}

// ---------------------------------------------------------------------------
// K1: single persistent kernel: LN + slot init + 3 iterations + updates.
// R7 post-mortem: per-iter ~36us = attention (~6) + TWO memory-side handoff
// round trips + serial updater weight-load chain while 504 blocks idle.
// Protocol (redundant distributed update):
//   - every block spins on cnt[it][b]==8 (coherent load) after storing its
//     partial, then REDUNDANTLY computes the full 8-slot update; next q' is
//     built in-block (LDS exchange) -> registers. No ready flag, no qU, no
//     slotsV: slots persist in registers (h0p/h1p).
//   - deadlock-free: all 512 blocks co-resident (2/CU, proven by R5-R7); a
//     block only waits on counters all 8 peer blocks bump unconditionally.
//   - it==2: only e==0 spins+updates (writes dout); others exit after cnt++.
__global__ __launch_bounds__(256, 2) void k_attn(
    const float* __restrict__ inp,
    const float* __restrict__ g_in, const float* __restrict__ b_in,
    const float* __restrict__ noise, const float* __restrict__ smu,
    const float* __restrict__ slsig,
    float* __restrict__ accPart, float* __restrict__ colPart,
    uintT* __restrict__ cnt,
    const float* __restrict__ wihP, const float* __restrict__ whhP,
    const float* __restrict__ w1P, const float* __restrict__ w2T,
    const float* __restrict__ wqT, const float* __restrict__ Wk,
    const float* __restrict__ wvT,
    const float* __restrict__ b_ih, const float* __restrict__ b_hh,
    const float* __restrict__ mb1, const float* __restrict__ mb2,
    const float* __restrict__ g_ml, const float* __restrict__ b_ml,
    const float* __restrict__ g_sl, const float* __restrict__ b_sl,
    float* __restrict__ dout)
{
  __shared__ __align__(16) ushortT XW[4][4096];
  const int tid = threadIdx.x;
  const int lane = tid & 63;
  const int wave = tid >> 6;
  const int l15 = lane & 15, q = lane >> 4;
  const int b = blockIdx.x >> 3;
  const int e = blockIdx.x & 7;        // eighth of the batch

  ushortT* xT = &XW[wave][0];

  // slot rows this wave owns for updates: ks0=wave, ks1=wave+4
  const int row0 = b * 8 + wave, row1 = row0 + 4;

  // initial slots, in registers (same fma/exp order as the old init)
  const float es = expf(slsig[lane]);
  float h0p = fmaf(es, noise[row0 * 64 + lane], smu[lane]);
  float h1p = fmaf(es, noise[row1 * 64 + lane], smu[lane]);

  // ---- in-kernel LN -> both chunks' A-frags in registers (as R7) ----
  short8 kA0[4][2], kA1[4][2];
  {
    const float4 g4 = *(const float4*)&g_in[l15 << 2];
    const float4 b4 = *(const float4*)&b_in[l15 << 2];
#pragma unroll
    for (int ch = 0; ch < 2; ++ch) {
      const int chunk = (e << 3) + (ch << 2) + wave;   // 0..63
      const float* rowbase = inp + (((long)b * NN + (chunk << 6)) << 6);
#pragma unroll
      for (int pass = 0; pass < 16; ++pass) {
        const int row = (pass << 2) + q;
        float4 x = *(const float4*)&rowbase[(row << 6) + (l15 << 2)];
        float s = x.x + x.y + x.z + x.w;
        s += __shfl_xor(s, 1); s += __shfl_xor(s, 2);
        s += __shfl_xor(s, 4); s += __shfl_xor(s, 8);
        const float mu = s * (1.f / 64.f);
        float4 dx = {x.x - mu, x.y - mu, x.z - mu, x.w - mu};
        float ss = dx.x * dx.x + dx.y * dx.y + dx.z * dx.z + dx.w * dx.w;
        ss += __shfl_xor(ss, 1); ss += __shfl_xor(ss, 2);
        ss += __shfl_xor(ss, 4); ss += __shfl_xor(ss, 8);
        const float rs = rsqrtf(ss * (1.f / 64.f) + LN_EPS);
        us4 p = {f2bf(dx.x * rs * g4.x + b4.x), f2bf(dx.y * rs * g4.y + b4.y),
                 f2bf(dx.z * rs * g4.z + b4.z), f2bf(dx.w * rs * g4.w + b4.w)};
        *(us4*)&xT[((((row >> 4) * 2 + (l15 >> 3)) << 6)
                    + (((l15 & 7) >> 1) << 4) + (row & 15)) * 8
                   + ((l15 & 1) << 2)] = p;
      }
      wait_lds();
#pragma unroll
      for (int mt = 0; mt < 4; ++mt)
#pragma unroll
        for (int kb = 0; kb < 2; ++kb) {
          short8 v = *(const short8*)&xT[((mt * 2 + kb) * 64 + lane) << 3];
          if (ch) kA1[mt][kb] = v; else kA0[mt][kb] = v;
        }
      wait_lds();
    }
  }

  short8 qB[2];

  // q' from this wave's 2 slot rows: LN_sl -> @Wq^T -> @Wk -> block LDS
  // exchange -> every lane's B-frag registers. Bit-identical math to the
  // old publish path (same fma order, f2bf at the same point).
  auto slots_to_qB = [&](float sv0, float sv1) {
    float* S = (float*)&XW[wave][0];          // wave-private floats [0..255]
    float* qS = (float*)&XW[0][1024];         // block-shared [8][64]
    float m0 = wredsum(sv0) * (1.f / 64.f);
    float d0 = sv0 - m0;
    float v0 = wredsum(d0 * d0) * (1.f / 64.f);
    const float sq0 = d0 * rsqrtf(v0 + LN_EPS) * g_sl[lane] + b_sl[lane];
    float m1 = wredsum(sv1) * (1.f / 64.f);
    float d1 = sv1 - m1;
    float v1 = wredsum(d1 * d1) * (1.f / 64.f);
    const float sq1 = d1 * rsqrtf(v1 + LN_EPS) * g_sl[lane] + b_sl[lane];
    S[lane] = sq0; S[64 + lane] = sq1;
    float qe0 = 0.f, qe1 = 0.f;
#pragma unroll 8
    for (int d = 0; d < 64; ++d) {
      const float wq = wqT[d * 64 + lane];
      qe0 = fmaf(S[d], wq, qe0);
      qe1 = fmaf(S[64 + d], wq, qe1);
    }
    S[128 + lane] = qe0; S[192 + lane] = qe1;
    float qp0 = 0.f, qp1 = 0.f;
#pragma unroll 8
    for (int e2 = 0; e2 < 64; ++e2) {
      const float wk = Wk[e2 * 64 + lane];
      qp0 = fmaf(S[128 + e2], wk, qp0);
      qp1 = fmaf(S[192 + e2], wk, qp1);
    }
    __syncthreads();
    qS[wave * 64 + lane] = qp0 * 0.125f;
    qS[(wave + 4) * 64 + lane] = qp1 * 0.125f;
    __syncthreads();
#pragma unroll
    for (int kb = 0; kb < 2; ++kb) {
      ushortT tmp[8];
#pragma unroll
      for (int j = 0; j < 8; ++j) {
        const int col = lane & 15;
        float v = (col < 8) ? qS[col * 64 + kb * 32 + ((lane >> 4) << 3) + j] : 0.f;
        tmp[j] = f2bf(v);
      }
      qB[kb] = *(short8*)tmp;
    }
    __syncthreads();
  };

  slots_to_qB(h0p, h1p);

  for (int it = 0; it < 3; ++it) {
    f32x4 accP[4];
#pragma unroll
    for (int nt = 0; nt < 4; ++nt) accP[nt] = (f32x4){0.f, 0.f, 0.f, 0.f};
    float csum = 0.f;

#pragma unroll
    for (int ch = 0; ch < 2; ++ch) {
      f32x4 accL[4];
#pragma unroll
      for (int mt = 0; mt < 4; ++mt) {
        const short8 a0 = ch ? kA1[mt][0] : kA0[mt][0];
        const short8 a1 = ch ? kA1[mt][1] : kA0[mt][1];
        accL[mt] = (f32x4){0.f, 0.f, 0.f, 0.f};
        accL[mt] = __builtin_amdgcn_mfma_f32_16x16x32_bf16(a0, qB[0], accL[mt], 0, 0, 0);
        accL[mt] = __builtin_amdgcn_mfma_f32_16x16x32_bf16(a1, qB[1], accL[mt], 0, 0, 0);
      }

      // in-LDS transpose: xn A-frags (j=f) -> PV B-frags (j=n), XOR-swizzled
      {
        const int h = ((lane >> 5) << 2) | (((lane & 15) >> 3) << 1) | ((lane >> 4) & 1);
        const int jp = lane & 7;
        const int lpA = (((lane >> 4) & 1) << 3) + (((lane & 15) >> 3) << 4);
#pragma unroll
        for (int mt = 0; mt < 4; ++mt)
#pragma unroll
          for (int kb = 0; kb < 2; ++kb) {
            const int fb = (kb * 4 + ((lane >> 5) << 1) + (mt >> 1)) << 9;
            const int lm = lpA + ((mt & 1) << 5);
            const short8 src8 = ch ? kA1[mt][kb] : kA0[mt][kb];
            const ushortT* src = (const ushortT*)&src8;
#pragma unroll
            for (int j = 0; j < 8; ++j)
              xT[fb + (((lm + j) ^ h) << 3) + jp] = src[j];
          }
      }
      short8 vB[4][2];
#pragma unroll
      for (int nt = 0; nt < 4; ++nt)
#pragma unroll
        for (int ks = 0; ks < 2; ++ks) {
          const int frag = nt * 2 + ks;
          const int hr = ((nt & 1) << 2) | (((lane >> 4) & 1) << 1) | ((lane >> 3) & 1);
          vB[nt][ks] = *(const short8*)&xT[(frag << 9) + ((lane ^ hr) << 3)];
        }

      // softmax over slots (cols 8..15 benign: q' cols zeroed)
      ushortT* attnF = &XW[wave][0];
#pragma unroll
      for (int mt = 0; mt < 4; ++mt) {
        float av[4];
#pragma unroll
        for (int r = 0; r < 4; ++r) {
          float lv = accL[mt][r];
          float mx = lv;
          mx = fmaxf(mx, __shfl_xor(mx, 1));
          mx = fmaxf(mx, __shfl_xor(mx, 2));
          mx = fmaxf(mx, __shfl_xor(mx, 4));
          float ev = __expf(lv - mx);
          float sv = ev;
          sv += __shfl_xor(sv, 1); sv += __shfl_xor(sv, 2); sv += __shfl_xor(sv, 4);
          float a = ev * (1.f / sv) + EPS;
          av[r] = a;
          csum += a;
        }
        us4 p = {f2bf(av[0]), f2bf(av[1]), f2bf(av[2]), f2bf(av[3])};
        *(us4*)&attnF[((((mt >> 1) << 6) + (((mt & 1) * 2 + (q >> 1)) << 4)
                        + l15) << 3) + ((q & 1) << 2)] = p;
      }

      short8 pA0 = *(const short8*)&attnF[(0 * 64 + lane) << 3];
      short8 pA1 = *(const short8*)&attnF[(1 * 64 + lane) << 3];

#pragma unroll
      for (int nt = 0; nt < 4; ++nt) {
        accP[nt] = __builtin_amdgcn_mfma_f32_16x16x32_bf16(pA0, vB[nt][0], accP[nt], 0, 0, 0);
        accP[nt] = __builtin_amdgcn_mfma_f32_16x16x32_bf16(pA1, vB[nt][1], accP[nt], 0, 0, 0);
      }
    }

    csum += __shfl_xor(csum, 16);
    csum += __shfl_xor(csum, 32);

    // cross-wave reduce in LDS, then one coherent store of the block partial
    float* accLw = (float*)&XW[wave][1024];
    float* colLw = (float*)&XW[wave][2048];
    if (q < 2) {
#pragma unroll
      for (int nt = 0; nt < 4; ++nt)
#pragma unroll
        for (int r = 0; r < 4; ++r)
          accLw[(q * 4 + r) * 64 + nt * 16 + l15] = accP[nt][r];
    }
    if (q == 0 && l15 < 8) colLw[l15] = csum;
    __syncthreads();

    float* apIt = accPart + ((long)(it * 64 + b) * 8 + e) * 512;
    float* cpIt = colPart + ((long)(it * 64 + b) * 8 + e) * 8;
    {
      const int o = tid * 2;
      f32x2 s;
#pragma unroll
      for (int r = 0; r < 2; ++r) {
        const int oo = o + r;
        s[r] = *((float*)&XW[0][1024] + oo) + *((float*)&XW[1][1024] + oo)
             + *((float*)&XW[2][1024] + oo) + *((float*)&XW[3][1024] + oo);
      }
      store2_coh(&apIt[o], s);
    }
    if (tid < 8) {
      float s = *((float*)&XW[0][2048] + tid) + *((float*)&XW[1][2048] + tid)
              + *((float*)&XW[2][2048] + tid) + *((float*)&XW[3][2048] + tid);
      store1f_coh(&cpIt[tid], s);
    }

    drain_vm();
    __syncthreads();
    if (tid == 0) atomicAdd(&cnt[it * 64 + b], 1u);

    // final iteration: only e==0 needs the update (for dout)
    if (it == 2 && e != 0) return;

    // spin until all 8 peer blocks of this batch have stored their partials
    if (tid == 0) {
      while (load1u_coh(&cnt[it * 64 + b]) < 8u) __builtin_amdgcn_s_sleep(2);
    }
    __syncthreads();

    // ===== redundant slot update: every block, wave w -> rows w, w+4 =====
    const float* apB = accPart + (long)(it * 64 + b) * 8 * 512;
    const float* cpB = colPart + (long)(it * 64 + b) * 8 * 8;

    float csv0 = 0.f, csv1 = 0.f, t0 = 0.f, t1 = 0.f;
#pragma unroll
    for (int ee = 0; ee < 8; ++ee) {
      csv0 += cpB[ee * 8 + wave];
      csv1 += cpB[ee * 8 + wave + 4];
      t0 += apB[ee * 512 + wave * 64 + lane];
      t1 += apB[ee * 512 + (wave + 4) * 64 + lane];
    }
    t0 /= csv0; t1 /= csv1;
    const float h0 = h0p, h1 = h1p;

    float* S = (float*)&XW[wave][0];

    // updates = (t/csum) @ Wv^T  (f32 weights)
    S[256 + lane] = t0; S[320 + lane] = t1;
    float u0 = 0.f, u1 = 0.f;
#pragma unroll 4
    for (int f = 0; f < 64; ++f) {
      const float wv = wvT[f * 64 + lane];
      u0 = fmaf(S[256 + f], wv, u0);
      u1 = fmaf(S[320 + f], wv, u1);
    }

    S[lane] = u0; S[64 + lane] = u1; S[128 + lane] = h0; S[192 + lane] = h1;

    float gir0 = b_ih[lane], giz0 = b_ih[64 + lane], gin0 = b_ih[128 + lane];
    float ghr0 = b_hh[lane], ghz0 = b_hh[64 + lane], ghn0 = b_hh[128 + lane];
    float gir1 = gir0, giz1 = giz0, gin1 = gin0;
    float ghr1 = ghr0, ghz1 = ghz0, ghn1 = ghn0;
    const float4* wihP4 = (const float4*)wihP;
    const float4* whhP4 = (const float4*)whhP;
#pragma unroll 8
    for (int f = 0; f < 64; ++f) {
      const float4 wi = wihP4[f * 64 + lane];
      const float4 wh = whhP4[f * 64 + lane];
      const float a0 = S[f], a1 = S[64 + f], c0 = S[128 + f], c1 = S[192 + f];
      gir0 = fmaf(a0, wi.x, gir0); gir1 = fmaf(a1, wi.x, gir1);
      giz0 = fmaf(a0, wi.y, giz0); giz1 = fmaf(a1, wi.y, giz1);
      gin0 = fmaf(a0, wi.z, gin0); gin1 = fmaf(a1, wi.z, gin1);
      ghr0 = fmaf(c0, wh.x, ghr0); ghr1 = fmaf(c1, wh.x, ghr1);
      ghz0 = fmaf(c0, wh.y, ghz0); ghz1 = fmaf(c1, wh.y, ghz1);
      ghn0 = fmaf(c0, wh.z, ghn0); ghn1 = fmaf(c1, wh.z, ghn1);
    }
    const float r0 = 1.f / (1.f + expf(-(gir0 + ghr0)));
    const float z0 = 1.f / (1.f + expf(-(giz0 + ghz0)));
    const float n0 = tanhf(fmaf(r0, ghn0, gin0));
    const float hn0 = (1.f - z0) * n0 + z0 * h0;
    const float r1 = 1.f / (1.f + expf(-(gir1 + ghr1)));
    const float z1 = 1.f / (1.f + expf(-(giz1 + ghz1)));
    const float n1 = tanhf(fmaf(r1, ghn1, gin1));
    const float hn1 = (1.f - z1) * n1 + z1 * h1;

    float mu0 = wredsum(hn0) * (1.f / 64.f);
    float dx0 = hn0 - mu0;
    float va0 = wredsum(dx0 * dx0) * (1.f / 64.f);
    const float ln0 = dx0 * rsqrtf(va0 + LN_EPS) * g_ml[lane] + b_ml[lane];
    float mu1 = wredsum(hn1) * (1.f / 64.f);
    float dx1 = hn1 - mu1;
    float va1 = wredsum(dx1 * dx1) * (1.f / 64.f);
    const float ln1 = dx1 * rsqrtf(va1 + LN_EPS) * g_ml[lane] + b_ml[lane];
    S[256 + lane] = ln0; S[320 + lane] = ln1;

    float h1a0 = mb1[lane], h1b0 = mb1[64 + lane];
    float h1a1 = h1a0, h1b1 = h1b0;
    const f32x2* w1P2 = (const f32x2*)w1P;
#pragma unroll 8
    for (int f = 0; f < 64; ++f) {
      const f32x2 w = w1P2[f * 64 + lane];
      const float l0 = S[256 + f], l1 = S[320 + f];
      h1a0 = fmaf(l0, w.x, h1a0); h1a1 = fmaf(l1, w.x, h1a1);
      h1b0 = fmaf(l0, w.y, h1b0); h1b1 = fmaf(l1, w.y, h1b1);
    }
    h1a0 = fmaxf(h1a0, 0.f); h1b0 = fmaxf(h1b0, 0.f);
    h1a1 = fmaxf(h1a1, 0.f); h1b1 = fmaxf(h1b1, 0.f);
    S[lane] = h1a0; S[64 + lane] = h1b0;
    S[128 + lane] = h1a1; S[192 + lane] = h1b1;

    float o0 = mb2[lane], o1 = mb2[lane];
#pragma unroll 4
    for (int j = 0; j < 128; ++j) {
      const float w2v = w2T[j * 64 + lane];
      o0 = fmaf(S[j], w2v, o0);
      o1 = fmaf(S[128 + j], w2v, o1);
    }
    const float sn0 = hn0 + o0;
    const float sn1 = hn1 + o1;

    if (it == 2) {
      dout[row0 * 64 + lane] = sn0;
      dout[row1 * 64 + lane] = sn1;
      return;
    }
    h0p = sn0; h1p = sn1;
    slots_to_qB(sn0, sn1);
  }
}

// ---------------------------------------------------------------------------
extern "C" void kernel_launch(void* const* d_in, const int* in_sizes, int n_in,
                              void* d_out, int out_size, void* d_ws, size_t ws_size,
                              hipStream_t stream) {
  const float* inp   = (const float*)d_in[0];
  const float* noise = (const float*)d_in[1];
  const float* smu   = (const float*)d_in[2];
  const float* slsig = (const float*)d_in[3];
  const float* Wq    = (const float*)d_in[4];
  const float* Wk    = (const float*)d_in[5];
  const float* Wv    = (const float*)d_in[6];
  const float* w_ih  = (const float*)d_in[7];
  const float* w_hh  = (const float*)d_in[8];
  const float* b_ih  = (const float*)d_in[9];
  const float* b_hh  = (const float*)d_in[10];
  const float* w1    = (const float*)d_in[11];
  const float* b1    = (const float*)d_in[12];
  const float* w2    = (const float*)d_in[13];
  const float* b2    = (const float*)d_in[14];
  const float* g_in  = (const float*)d_in[15];
  const float* bi_in = (const float*)d_in[16];
  const float* g_sl  = (const float*)d_in[17];
  const float* bi_sl = (const float*)d_in[18];
  const float* g_ml  = (const float*)d_in[19];
  const float* bi_ml = (const float*)d_in[20];

  float* ws      = (float*)d_ws;
  float* ap      = ws + OFF_AP;
  float* cp      = ws + OFF_CP;
  float* wihP    = ws + OFF_WIHP;
  float* whhP    = ws + OFF_WHHP;
  float* w1P     = ws + OFF_W1P;
  float* w2T     = ws + OFF_W2T;
  float* wqT     = ws + OFF_WQT;
  float* wvT     = ws + OFF_WVT;
  uintT* cnt     = (uintT*)(ws + OFF_CNT);

  k_prep<<<225, 256, 0, stream>>>(w_ih, w_hh, w1, w2, Wq, Wv,
                                  wihP, whhP, w1P, w2T, wqT, wvT, cnt);
  k_attn<<<512, 256, 0, stream>>>(inp, g_in, bi_in, noise, smu, slsig,
                                  ap, cp, cnt,
                                  wihP, whhP, w1P, w2T, wqT, Wk, wvT,
                                  b_ih, b_hh, b1, b2, g_ml, bi_ml, g_sl, bi_sl,
                                  (float*)d_out);
}